// Round 4
// baseline (1946.832 us; speedup 1.0000x reference)
//
#include <hip/hip_runtime.h>
#include <hip/hip_fp16.h>

#define BATCH 16
#define CH    64
#define TLEN  200
#define NP    30
#define HID   128
#define G4    512            // 4*HID
#define NSEQ  (BATCH * NP)   // 480

__device__ __forceinline__ float dot4(float4 a, float4 b) {
    return a.x * b.x + a.y * b.y + a.z * b.z + a.w * b.w;
}

// Pin each 32-bit component: "+v" on a float is one VGPR (supported), unlike
// a tied 128-bit float4 (R3 compile failure). The pinned values are asm
// outputs -> the allocator cannot re-materialize the originating loads
// inside the loop (the R1/R2 failure mode: W_hh re-streamed from L2 at the
// 36.9 TB/s ceiling every timestep).
#define PIN4(v) asm volatile("" : "+v"(v.x), "+v"(v.y), "+v"(v.z), "+v"(v.w))

__device__ __forceinline__ float sigm_fast(float x) {
    return __builtin_amdgcn_rcpf(1.0f + __expf(-x));
}

__device__ __forceinline__ float tanh_fast(float x) {
    float xc = fminf(15.0f, fmaxf(-15.0f, x));
    float e = __expf(2.0f * xc);
    return (e - 1.0f) * __builtin_amdgcn_rcpf(e + 1.0f);
}

// ---------------------------------------------------------------------------
// Phase 1: xg[n][t][g] = sum_c x[b][c][t][p] * W_ih[g][c] + b_ih[g] + b_hh[g]
// waves_per_eu(4,4): 128-VGPR budget -> 64 weight regs resident, 2 blocks/CU.
// ---------------------------------------------------------------------------
template <typename XT>
__global__ __attribute__((amdgpu_flat_work_group_size(512, 512)))
__attribute__((amdgpu_waves_per_eu(4, 4)))
void xg_kernel(
    const float* __restrict__ x, const float* __restrict__ W_ih,
    const float* __restrict__ b_ih, const float* __restrict__ b_hh,
    XT* __restrict__ xg)
{
    const int t   = blockIdx.x;   // 0..199
    const int b   = blockIdx.y;   // 0..15
    const int tid = threadIdx.x;  // 0..511

    __shared__ float xs[NP][CH];

    {   // cooperative load of x[b, :, t, :]
        const int c = tid >> 3;
        const int l = tid & 7;
        const float* xr = x + ((size_t)(b * CH + c) * TLEN + t) * NP;
        for (int p = l; p < NP; p += 8) xs[p][c] = xr[p];
    }

    const int g = tid;
    const float4* wr = (const float4*)(W_ih + (size_t)g * CH);
#define LWI(i) float4 w##i = wr[i]; PIN4(w##i);
    LWI(0) LWI(1) LWI(2) LWI(3) LWI(4) LWI(5) LWI(6) LWI(7)
    LWI(8) LWI(9) LWI(10) LWI(11) LWI(12) LWI(13) LWI(14) LWI(15)
#undef LWI
    const float bias = b_ih[g] + b_hh[g];
    __syncthreads();

    for (int p = 0; p < NP; ++p) {
        const float4* xv = (const float4*)(xs[p]);
        float a0 = 0.f, a1 = 0.f, a2 = 0.f, a3 = 0.f;
        a0 += dot4(w0,  xv[0]);  a1 += dot4(w1,  xv[1]);
        a2 += dot4(w2,  xv[2]);  a3 += dot4(w3,  xv[3]);
        a0 += dot4(w4,  xv[4]);  a1 += dot4(w5,  xv[5]);
        a2 += dot4(w6,  xv[6]);  a3 += dot4(w7,  xv[7]);
        a0 += dot4(w8,  xv[8]);  a1 += dot4(w9,  xv[9]);
        a2 += dot4(w10, xv[10]); a3 += dot4(w11, xv[11]);
        a0 += dot4(w12, xv[12]); a1 += dot4(w13, xv[13]);
        a2 += dot4(w14, xv[14]); a3 += dot4(w15, xv[15]);
        const float acc = bias + ((a0 + a1) + (a2 + a3));
        const int n = b * NP + p;
        xg[((size_t)n * TLEN + t) * G4 + g] = (XT)acc;
    }
}

// ---------------------------------------------------------------------------
// Phase 2: recurrent LSTM. One block = 2 sequences (240 blocks ~ 1 block/CU).
// waves_per_eu(2,2): 256-VGPR budget so the 128 weight VGPRs stay resident.
// ---------------------------------------------------------------------------
template <typename XT>
__global__ __attribute__((amdgpu_flat_work_group_size(512, 512)))
__attribute__((amdgpu_waves_per_eu(2, 2)))
void lstm_kernel(
    const XT* __restrict__ xg, const float* __restrict__ W_hh,
    const float* __restrict__ W_fc, const float* __restrict__ b_fc,
    float* __restrict__ out)
{
    const int pair = blockIdx.x;
    const int n0 = pair * 2;
    const int n1 = n0 + 1;
    const int tid = threadIdx.x;

    __shared__ float hs[2][HID];
    __shared__ float cs[2][HID];
    __shared__ float gl[2][G4];

    if (tid < 2 * HID) {
        hs[tid >> 7][tid & 127] = 0.0f;
        cs[tid >> 7][tid & 127] = 0.0f;
    }

    const float4* wr = (const float4*)(W_hh + (size_t)tid * HID);
#define LWH(i) float4 w##i = wr[i]; PIN4(w##i);
    LWH(0)  LWH(1)  LWH(2)  LWH(3)  LWH(4)  LWH(5)  LWH(6)  LWH(7)
    LWH(8)  LWH(9)  LWH(10) LWH(11) LWH(12) LWH(13) LWH(14) LWH(15)
    LWH(16) LWH(17) LWH(18) LWH(19) LWH(20) LWH(21) LWH(22) LWH(23)
    LWH(24) LWH(25) LWH(26) LWH(27) LWH(28) LWH(29) LWH(30) LWH(31)
#undef LWH

    const XT* p0 = xg + (size_t)n0 * TLEN * G4 + tid;
    const XT* p1 = xg + (size_t)n1 * TLEN * G4 + tid;
    float xa = (float)p0[0];
    float xb = (float)p1[0];
    const float4* h0 = (const float4*)hs[0];
    const float4* h1 = (const float4*)hs[1];
    __syncthreads();

    for (int t = 0; t < TLEN; ++t) {
        float nxa = 0.f, nxb = 0.f;
        if (t + 1 < TLEN) {
            nxa = (float)p0[(size_t)(t + 1) * G4];
            nxb = (float)p1[(size_t)(t + 1) * G4];
        }

        float a0 = 0.f, a1 = 0.f, b0 = 0.f, b1 = 0.f;
#define DW(i, p) { float4 ha = h0[i]; float4 hb = h1[i]; \
                   a##p += dot4(w##i, ha); b##p += dot4(w##i, hb); }
        DW(0,0)  DW(1,1)  DW(2,0)  DW(3,1)  DW(4,0)  DW(5,1)  DW(6,0)  DW(7,1)
        DW(8,0)  DW(9,1)  DW(10,0) DW(11,1) DW(12,0) DW(13,1) DW(14,0) DW(15,1)
        DW(16,0) DW(17,1) DW(18,0) DW(19,1) DW(20,0) DW(21,1) DW(22,0) DW(23,1)
        DW(24,0) DW(25,1) DW(26,0) DW(27,1) DW(28,0) DW(29,1) DW(30,0) DW(31,1)
#undef DW
        gl[0][tid] = xa + (a0 + a1);
        gl[1][tid] = xb + (b0 + b1);
        __syncthreads();

        if (tid < 2 * HID) {
            const int s = tid >> 7, j = tid & 127;
            const float gi = gl[s][j];
            const float gf = gl[s][HID + j];
            const float gg = gl[s][2 * HID + j];
            const float go = gl[s][3 * HID + j];
            const float i = sigm_fast(gi);
            const float f = sigm_fast(gf);
            const float gt = tanh_fast(gg);
            const float o = sigm_fast(go);
            const float cn = f * cs[s][j] + i * gt;
            cs[s][j] = cn;
            hs[s][j] = o * tanh_fast(cn);
        }
        __syncthreads();
        xa = nxa;
        xb = nxb;
    }

    if (tid < 2 * CH) {
        const int s = tid >> 6, ch = tid & 63;
        const float4* wf = (const float4*)(W_fc + (size_t)ch * HID);
        const float4* hv = (const float4*)hs[s];
        float a0 = 0.f, a1 = 0.f;
#pragma unroll
        for (int j = 0; j < 32; j += 2) {
            a0 += dot4(wf[j], hv[j]);
            a1 += dot4(wf[j + 1], hv[j + 1]);
        }
        out[(size_t)(n0 + s) * CH + ch] = a0 + a1 + b_fc[ch];
    }
}

extern "C" void kernel_launch(void* const* d_in, const int* in_sizes, int n_in,
                              void* d_out, int out_size, void* d_ws, size_t ws_size,
                              hipStream_t stream) {
    (void)in_sizes; (void)n_in; (void)out_size;
    const float* x    = (const float*)d_in[0];
    const float* W_ih = (const float*)d_in[1];
    const float* W_hh = (const float*)d_in[2];
    const float* b_ih = (const float*)d_in[3];
    const float* b_hh = (const float*)d_in[4];
    const float* W_fc = (const float*)d_in[5];
    const float* b_fc = (const float*)d_in[6];
    float* out = (float*)d_out;

    const size_t need_f32 = (size_t)NSEQ * TLEN * G4 * sizeof(float);  // 196.6 MB
    if (ws_size >= need_f32) {
        float* xg = (float*)d_ws;
        xg_kernel<float><<<dim3(TLEN, BATCH), 512, 0, stream>>>(x, W_ih, b_ih, b_hh, xg);
        lstm_kernel<float><<<NSEQ / 2, 512, 0, stream>>>(xg, W_hh, W_fc, b_fc, out);
    } else {
        __half* xg = (__half*)d_ws;
        xg_kernel<__half><<<dim3(TLEN, BATCH), 512, 0, stream>>>(x, W_ih, b_ih, b_hh, xg);
        lstm_kernel<__half><<<NSEQ / 2, 512, 0, stream>>>(xg, W_hh, W_fc, b_fc, out);
    }
}

// Round 5
// 453.559 us; speedup vs baseline: 4.2923x; 4.2923x over previous
//
#include <hip/hip_runtime.h>

#define BATCH 16
#define CH    64
#define TLEN  200
#define NP    30
#define HID   128
#define G4    512            // 4*HID
#define NSEQ  (BATCH * NP)   // 480

typedef _Float16 f16x2 __attribute__((ext_vector_type(2)));
typedef _Float16 f16x8 __attribute__((ext_vector_type(8)));

#if __has_builtin(__builtin_amdgcn_fdot2)
#define FDOT2(w, h, a) __builtin_amdgcn_fdot2((w), (h), (a), false)
#else
#define FDOT2(w, h, a) ((a) + (float)(w)[0] * (float)(h)[0] + (float)(w)[1] * (float)(h)[1])
#endif

__device__ __forceinline__ float sigm_fast(float x) {
    return __builtin_amdgcn_rcpf(1.0f + __expf(-x));
}
__device__ __forceinline__ float tanh_fast(float x) {
    float xc = fminf(15.0f, fmaxf(-15.0f, x));
    float e = __expf(2.0f * xc);
    return (e - 1.0f) * __builtin_amdgcn_rcpf(e + 1.0f);
}

// ---------------------------------------------------------------------------
// Phase 1: xg[n][t][g] = dot(x[b,:,t,p], W_ih[g,:]) + b_ih[g] + b_hh[g]
// LDS-tiled GEMM. Block = (b, 2 t-values). W_ih fp32 in LDS (128 KB), x tile
// 16 KB. Thread = 8 gates x 8 positions with 64 loop-carried accumulators
// (registers the compiler reliably keeps). All W reuse is explicit LDS reads
// -> no invariant-load remat pathology (R1-R4).
// ---------------------------------------------------------------------------
template <typename XT>
__global__ __launch_bounds__(512) void xg_kernel(
    const float* __restrict__ x, const float* __restrict__ W_ih,
    const float* __restrict__ b_ih, const float* __restrict__ b_hh,
    XT* __restrict__ xg)
{
    const int t0  = blockIdx.x * 2;   // 0,2,..,198
    const int b   = blockIdx.y;       // 0..15
    const int tid = threadIdx.x;      // 0..511

    __shared__ float ws[CH][G4];      // [k][g]  128 KB
    __shared__ float xs[CH][64];      // [k][pos], pos = tt*32 + p (p<30; 30,31 pad)

    // stage W_ih (coalesced flat read; conflicted LDS writes are once-only)
    {
        const float4* W4 = (const float4*)W_ih;
#pragma unroll
        for (int i = 0; i < 16; ++i) {
            float4 v = W4[i * 512 + tid];
            int base = 4 * (i * 512 + tid);
            int g = base >> 6;          // /CH
            int k = base & 63;
            ws[k][g] = v.x; ws[k + 1][g] = v.y; ws[k + 2][g] = v.z; ws[k + 3][g] = v.w;
        }
    }
    // stage x[b, :, t0:t0+2, :]
    {
        const int c = tid >> 3, sub = tid & 7;
#pragma unroll
        for (int tt = 0; tt < 2; ++tt) {
            const float* xr = x + ((size_t)(b * CH + c) * TLEN + (t0 + tt)) * NP;
            for (int p = sub; p < NP; p += 8) xs[c][tt * 32 + p] = xr[p];
        }
    }

    const int gq   = tid & 63;        // gate base lane
    const int posq = tid >> 6;        // 0..7 -> 8 positions each
    const int pos0 = posq * 8;

    float bias[8];
#pragma unroll
    for (int j = 0; j < 8; ++j) {
        int g = gq + 64 * j;
        bias[j] = b_ih[g] + b_hh[g];
    }
    __syncthreads();

    float acc[8][8];
#pragma unroll
    for (int j = 0; j < 8; ++j)
#pragma unroll
        for (int i = 0; i < 8; ++i) acc[j][i] = 0.f;

#pragma unroll 4
    for (int k = 0; k < CH; ++k) {
        float w[8];
#pragma unroll
        for (int j = 0; j < 8; ++j) w[j] = ws[k][gq + 64 * j];   // lanes stride-1: conflict-free
        float4 xlo = *(const float4*)&xs[k][pos0];                // broadcast within wave
        float4 xhi = *(const float4*)&xs[k][pos0 + 4];
        float xv[8] = {xlo.x, xlo.y, xlo.z, xlo.w, xhi.x, xhi.y, xhi.z, xhi.w};
#pragma unroll
        for (int j = 0; j < 8; ++j)
#pragma unroll
            for (int i = 0; i < 8; ++i) acc[j][i] = fmaf(w[j], xv[i], acc[j][i]);
    }

    // write out (skip pad positions p>=30); lanes (gq) consecutive -> coalesced
#pragma unroll
    for (int i = 0; i < 8; ++i) {
        int pos = pos0 + i;
        int tt = pos >> 5, p = pos & 31;
        if (p >= NP) continue;
        int n = b * NP + p;
        size_t rowbase = ((size_t)n * TLEN + (t0 + tt)) * G4;
#pragma unroll
        for (int j = 0; j < 8; ++j) {
            int g = gq + 64 * j;
            xg[rowbase + g] = (XT)(acc[j][i] + bias[j]);
        }
    }
}

// ---------------------------------------------------------------------------
// Phase 2: recurrent LSTM. Block = 2 sequences, 240 blocks (~1/CU).
// W_hh as fp16 in LDS (128 KB), blocked layout wB[(k8)*512 + g][8 halves] so
// thread g's per-step reads are stride-1 ds_read_b128 (conflict-free).
// Dots via v_dot2_f32_f16 (fp32 accumulate). h fp16 in LDS, c fp32 in regs.
// ---------------------------------------------------------------------------
template <typename XT>
__global__ __launch_bounds__(512) void lstm_kernel(
    const XT* __restrict__ xg, const float* __restrict__ W_hh,
    const float* __restrict__ W_fc, const float* __restrict__ b_fc,
    float* __restrict__ out)
{
    const int pair = blockIdx.x;      // 0..239
    const int n0 = pair * 2;
    const int tid = threadIdx.x;      // 0..511 = gate index
    const int g = tid;

    __shared__ _Float16 wB[16 * G4 * 8];   // [k8][g][8 halves] 128 KB
    __shared__ _Float16 h2s[2][HID];       // h as fp16, [seq][hid]
    __shared__ float gl[2][G4];            // gate pre-activations

    // stage W_hh row g -> fp16 blocked layout (writes stride-1 b128: conflict-free)
    {
        const float4* row = (const float4*)(W_hh + (size_t)g * HID);
#pragma unroll
        for (int j8 = 0; j8 < 16; ++j8) {
            float4 f0 = row[2 * j8], f1 = row[2 * j8 + 1];
            f16x8 v = {(_Float16)f0.x, (_Float16)f0.y, (_Float16)f0.z, (_Float16)f0.w,
                       (_Float16)f1.x, (_Float16)f1.y, (_Float16)f1.z, (_Float16)f1.w};
            *(f16x8*)&wB[((size_t)j8 * G4 + g) * 8] = v;
        }
    }
    if (tid < 2 * HID) {
        ((_Float16*)h2s)[tid] = (_Float16)0.f;
    }
    // c-state lives in registers of update threads (tid<128: 2 hids each)
    float c0 = 0.f, c1 = 0.f;

    const XT* pa = xg + (size_t)n0 * TLEN * G4 + g;
    const XT* pb = xg + (size_t)(n0 + 1) * TLEN * G4 + g;
    float xa = (float)pa[0];
    float xb = (float)pb[0];
    __syncthreads();

    for (int t = 0; t < TLEN; ++t) {
        float nxa = 0.f, nxb = 0.f;
        if (t + 1 < TLEN) {
            nxa = (float)pa[(size_t)(t + 1) * G4];
            nxb = (float)pb[(size_t)(t + 1) * G4];
        }

        float acc0 = xa, acc1 = xb;
        const _Float16* wp = &wB[(size_t)g * 8];
#pragma unroll
        for (int j8 = 0; j8 < 16; ++j8) {
            f16x8 wv = *(const f16x8*)(wp + (size_t)j8 * G4 * 8);   // stride-1 b128
            f16x8 h0 = *(const f16x8*)&h2s[0][j8 * 8];              // broadcast
            f16x8 h1 = *(const f16x8*)&h2s[1][j8 * 8];              // broadcast
            f16x2 w0 = __builtin_shufflevector(wv, wv, 0, 1);
            f16x2 w1 = __builtin_shufflevector(wv, wv, 2, 3);
            f16x2 w2 = __builtin_shufflevector(wv, wv, 4, 5);
            f16x2 w3 = __builtin_shufflevector(wv, wv, 6, 7);
            f16x2 a0 = __builtin_shufflevector(h0, h0, 0, 1);
            f16x2 a1 = __builtin_shufflevector(h0, h0, 2, 3);
            f16x2 a2 = __builtin_shufflevector(h0, h0, 4, 5);
            f16x2 a3 = __builtin_shufflevector(h0, h0, 6, 7);
            f16x2 b0v = __builtin_shufflevector(h1, h1, 0, 1);
            f16x2 b1v = __builtin_shufflevector(h1, h1, 2, 3);
            f16x2 b2v = __builtin_shufflevector(h1, h1, 4, 5);
            f16x2 b3v = __builtin_shufflevector(h1, h1, 6, 7);
            acc0 = FDOT2(w0, a0, acc0); acc0 = FDOT2(w1, a1, acc0);
            acc0 = FDOT2(w2, a2, acc0); acc0 = FDOT2(w3, a3, acc0);
            acc1 = FDOT2(w0, b0v, acc1); acc1 = FDOT2(w1, b1v, acc1);
            acc1 = FDOT2(w2, b2v, acc1); acc1 = FDOT2(w3, b3v, acc1);
        }
        gl[0][g] = acc0;
        gl[1][g] = acc1;
        __syncthreads();

        if (tid < 2 * HID / 2) {        // 128 threads: 2 seqs x 64 hid-pairs
            const int s = tid >> 6, j2 = tid & 63, j = 2 * j2;
            float gi0 = gl[s][j],           gi1 = gl[s][j + 1];
            float gf0 = gl[s][HID + j],     gf1 = gl[s][HID + j + 1];
            float gg0 = gl[s][2 * HID + j], gg1 = gl[s][2 * HID + j + 1];
            float go0 = gl[s][3 * HID + j], go1 = gl[s][3 * HID + j + 1];
            c0 = sigm_fast(gf0) * c0 + sigm_fast(gi0) * tanh_fast(gg0);
            c1 = sigm_fast(gf1) * c1 + sigm_fast(gi1) * tanh_fast(gg1);
            float h0 = sigm_fast(go0) * tanh_fast(c0);
            float h1 = sigm_fast(go1) * tanh_fast(c1);
            *(f16x2*)&h2s[s][j] = (f16x2){(_Float16)h0, (_Float16)h1};
        }
        __syncthreads();
        xa = nxa;
        xb = nxb;
    }

    // FC epilogue: out[n][ch] = h . W_fc[ch] + b_fc[ch]
    if (tid < 2 * CH) {
        const int s = tid >> 6, ch = tid & 63;
        const float4* wf = (const float4*)(W_fc + (size_t)ch * HID);
        float acc = b_fc[ch];
#pragma unroll
        for (int j2 = 0; j2 < 32; ++j2) {
            float4 w4 = wf[j2];
            acc += w4.x * (float)h2s[s][4 * j2]     + w4.y * (float)h2s[s][4 * j2 + 1]
                 + w4.z * (float)h2s[s][4 * j2 + 2] + w4.w * (float)h2s[s][4 * j2 + 3];
        }
        out[(size_t)(n0 + s) * CH + ch] = acc;
    }
}

extern "C" void kernel_launch(void* const* d_in, const int* in_sizes, int n_in,
                              void* d_out, int out_size, void* d_ws, size_t ws_size,
                              hipStream_t stream) {
    (void)in_sizes; (void)n_in; (void)out_size;
    const float* x    = (const float*)d_in[0];
    const float* W_ih = (const float*)d_in[1];
    const float* W_hh = (const float*)d_in[2];
    const float* b_ih = (const float*)d_in[3];
    const float* b_hh = (const float*)d_in[4];
    const float* W_fc = (const float*)d_in[5];
    const float* b_fc = (const float*)d_in[6];
    float* out = (float*)d_out;

    const size_t need_f32 = (size_t)NSEQ * TLEN * G4 * sizeof(float);  // 196.6 MB
    if (ws_size >= need_f32) {
        float* xg = (float*)d_ws;
        xg_kernel<float><<<dim3(TLEN / 2, BATCH), 512, 0, stream>>>(x, W_ih, b_ih, b_hh, xg);
        lstm_kernel<float><<<NSEQ / 2, 512, 0, stream>>>(xg, W_hh, W_fc, b_fc, out);
    } else {
        _Float16* xg = (_Float16*)d_ws;
        xg_kernel<_Float16><<<dim3(TLEN / 2, BATCH), 512, 0, stream>>>(x, W_ih, b_ih, b_hh, xg);
        lstm_kernel<_Float16><<<NSEQ / 2, 512, 0, stream>>>(xg, W_hh, W_fc, b_fc, out);
    }
}